// Round 1
// baseline (402.111 us; speedup 1.0000x reference)
//
#include <hip/hip_runtime.h>

// Problem constants (fixed by the reference): B=512 graphs, NA=16, NC=256, D=256.
#define NGR 512
#define NA_ 16
#define NC_ 256
#define DD 256
#define SCALE 0.0625f

typedef __attribute__((ext_vector_type(8))) short bfrag;
typedef __attribute__((ext_vector_type(4))) float fx4;

static __device__ __forceinline__ unsigned short f2b(float f) {
  unsigned u = __builtin_bit_cast(unsigned, f);
  u += 0x7FFFu + ((u >> 16) & 1u);
  return (unsigned short)(u >> 16);
}
static __device__ __forceinline__ float b2f(unsigned short s) {
  unsigned u = ((unsigned)s) << 16;
  return __builtin_bit_cast(float, u);
}

// ---------------- prep: bf16 weight copies ----------------
// ws wbf layout: [0]=Wq_ads, [1]=Wk_ads, [2]=Wv_ads, [3]=Wv_cat (as-is [g][e]),
//                [4]=Wk_cat^T ([e][d]), [5]=Wq_cat^T ([e][d])
__global__ __launch_bounds__(256) void prepW(const float* __restrict__ wq_a,
    const float* __restrict__ wk_a, const float* __restrict__ wv_a,
    const float* __restrict__ wv_c, const float* __restrict__ wk_c,
    const float* __restrict__ wq_c, unsigned short* __restrict__ wbf) {
  int idx = blockIdx.x * 256 + threadIdx.x;   // 0 .. 6*65536-1
  int m = idx >> 16, i = idx & 65535;
  float v;
  if (m == 0) v = wq_a[i];
  else if (m == 1) v = wk_a[i];
  else if (m == 2) v = wv_a[i];
  else if (m == 3) v = wv_c[i];
  else {
    int e = i >> 8, d = i & 255;               // transposed: out[e][d] = W[d][e]
    v = (m == 4) ? wk_c[d * DD + e] : wq_c[d * DD + e];
  }
  wbf[idx] = f2b(v);
}

// ---------------- kernel A: ads projections q/k/v_ads (bf16 out) ----------------
__global__ __launch_bounds__(256) void kA(const float* __restrict__ h_ads,
    const unsigned short* __restrict__ wbf,
    const float* __restrict__ bq, const float* __restrict__ bk, const float* __restrict__ bv,
    unsigned short* __restrict__ q_ads, unsigned short* __restrict__ k_ads,
    unsigned short* __restrict__ v_ads) {
  __shared__ unsigned short sH[64][264];
  const int t = threadIdx.x, blk = blockIdx.x;
  const int row0 = blk * 64;
#pragma unroll
  for (int rep = 0; rep < 16; ++rep) {
    int i4 = rep * 256 + t;
    int r = i4 >> 6, c4 = (i4 & 63) * 4;
    const float4 v = *(const float4*)&h_ads[(size_t)(row0 + r) * DD + c4];
    sH[r][c4 + 0] = f2b(v.x); sH[r][c4 + 1] = f2b(v.y);
    sH[r][c4 + 2] = f2b(v.z); sH[r][c4 + 3] = f2b(v.w);
  }
  __syncthreads();
  const int w = t >> 6, l = t & 63;
  const int lr = l & 15, lg = l >> 4, lk = lg * 8;
#pragma unroll
  for (int m = 0; m < 3; ++m) {
    const unsigned short* wm = wbf + m * 65536;
    const float* bb = (m == 0) ? bq : (m == 1) ? bk : bv;
    unsigned short* om = (m == 0) ? q_ads : (m == 1) ? k_ads : v_ads;
    for (int nt = 0; nt < 16; ++nt) {
      fx4 acc = {0.f, 0.f, 0.f, 0.f};
      int col = nt * 16 + lr;
#pragma unroll
      for (int kt = 0; kt < 8; ++kt) {
        bfrag a = *(const bfrag*)&sH[w * 16 + lr][kt * 32 + lk];
        bfrag b = *(const bfrag*)&wm[(size_t)col * DD + kt * 32 + lk];
        acc = __builtin_amdgcn_mfma_f32_16x16x32_bf16(a, b, acc, 0, 0, 0);
      }
      float bias = bb[col];
#pragma unroll
      for (int jj = 0; jj < 4; ++jj) {
        int r = w * 16 + lg * 4 + jj;
        om[(size_t)(row0 + r) * DD + col] = f2b(acc[jj] + bias);
      }
    }
  }
}

// ---------------- kernel B: per-graph attention + outputs ----------------
__global__ __launch_bounds__(256) void kB(
    const float* __restrict__ h_ads, const float* __restrict__ h_cat,
    const unsigned short* __restrict__ wbf,
    const float* __restrict__ bq_cat, const float* __restrict__ bk_cat,
    const float* __restrict__ bv_cat,
    const unsigned short* __restrict__ q_ads, const unsigned short* __restrict__ k_ads,
    const unsigned short* __restrict__ v_ads,
    float* __restrict__ out_ads, float* __restrict__ out_cat) {
  // LDS regions (time-multiplexed):
  // R1 @0     (16896B): ph0-1 {sQ,sK} -> ph2 sHrm[32][264] -> ph3+ sP[16][264]
  // R2 @16896 (20480B): ph1-2 {sT,sU} -> ph4 sHT[256][40] -> ph5 sV[16][264]
  // R3 @37376 (24832B): ph2-3 sS[16][260]f32 (ph4 alias: sR[16][264]) ; sP2[256][16] @54016
  __shared__ __align__(16) char smem[62208];
  __shared__ float sAB[32];       // alpha[16], beta[16]
  __shared__ float sRed[16][4];

  unsigned short* const R1 = (unsigned short*)smem;
  unsigned short* const R2 = (unsigned short*)(smem + 16896);
  float* const sS = (float*)(smem + 37376);
  unsigned short* const sR = (unsigned short*)(smem + 37376);
  unsigned short* const sP2 = (unsigned short*)(smem + 54016);

  unsigned short* const sQ = R1;
  unsigned short* const sK = R1 + 4224;
  unsigned short* const sHrm = R1;
  unsigned short* const sP = R1;
  unsigned short* const sT = R2;
  unsigned short* const sU = R2 + 4224;
  unsigned short* const sHT = R2;
  unsigned short* const sV = R2;

  const int t = threadIdx.x, b = blockIdx.x;
  const int w = t >> 6, l = t & 63;
  const int lr = l & 15, lg = l >> 4, lk = lg * 8;

  // ---- ph0: load q_ads, k_ads for graph b ----
  {
    const unsigned short* qg = q_ads + (size_t)b * NA_ * DD;
    const unsigned short* kg = k_ads + (size_t)b * NA_ * DD;
#pragma unroll
    for (int rep = 0; rep < 4; ++rep) {
      int i4 = rep * 256 + t;
      int r = i4 >> 6, c = (i4 & 63) * 4;
      *(uint2*)&sQ[r * 264 + c] = *(const uint2*)&qg[r * DD + c];
      *(uint2*)&sK[r * 264 + c] = *(const uint2*)&kg[r * DD + c];
    }
  }
  __syncthreads();

  // ---- ph1: t = q_ads @ Wk_cat, u = k_ads @ Wq_cat ; alpha, beta ----
  {
    const unsigned short* wT = (w < 2) ? (wbf + 4 * 65536) : (wbf + 5 * 65536);
    const unsigned short* src = (w < 2) ? sQ : sK;
    unsigned short* dst = (w < 2) ? sT : sU;
    int tb = (w & 1) * 8;
#pragma unroll
    for (int i = 0; i < 8; ++i) {
      int tile = tb + i;
      fx4 acc = {0.f, 0.f, 0.f, 0.f};
#pragma unroll
      for (int kt = 0; kt < 8; ++kt) {
        bfrag a = *(const bfrag*)&src[lr * 264 + kt * 32 + lk];
        bfrag bfr = *(const bfrag*)&wT[(size_t)(tile * 16 + lr) * DD + kt * 32 + lk];
        acc = __builtin_amdgcn_mfma_f32_16x16x32_bf16(a, bfr, acc, 0, 0, 0);
      }
#pragma unroll
      for (int jj = 0; jj < 4; ++jj)
        dst[(lg * 4 + jj) * 264 + tile * 16 + lr] = f2b(acc[jj]);
    }
    if (w < 2) {  // wave0: alpha = q.bk_cat ; wave1: beta = k.bq_cat
      const unsigned short* s = (w == 0) ? sQ : sK;
      const float* bias = (w == 0) ? bk_cat : bq_cat;
      int row = l >> 2, seg = l & 3;
      float acc = 0.f;
      for (int d = seg * 64; d < seg * 64 + 64; ++d)
        acc += b2f(s[row * 264 + d]) * bias[d];
      acc += __shfl_xor(acc, 1);
      acc += __shfl_xor(acc, 2);
      if (seg == 0) sAB[w * 16 + row] = acc;
    }
  }

  // ---- ph2: scores S[16][256] (f32) and online P2 (softmax over 16 a's) ----
  for (int ch = 0; ch < 8; ++ch) {
    __syncthreads();
#pragma unroll
    for (int rep = 0; rep < 8; ++rep) {
      int i4 = rep * 256 + t;
      int r = i4 >> 6, c4 = (i4 & 63) * 4;
      float4 v = *(const float4*)&h_cat[((size_t)b * NC_ + ch * 32 + r) * DD + c4];
      sHrm[r * 264 + c4 + 0] = f2b(v.x); sHrm[r * 264 + c4 + 1] = f2b(v.y);
      sHrm[r * 264 + c4 + 2] = f2b(v.z); sHrm[r * 264 + c4 + 3] = f2b(v.w);
    }
    __syncthreads();
    if (w < 2) {
      fx4 acc = {0.f, 0.f, 0.f, 0.f};
#pragma unroll
      for (int kt = 0; kt < 8; ++kt) {
        bfrag a = *(const bfrag*)&sT[lr * 264 + kt * 32 + lk];
        bfrag bfr = *(const bfrag*)&sHrm[(w * 16 + lr) * 264 + kt * 32 + lk];
        acc = __builtin_amdgcn_mfma_f32_16x16x32_bf16(a, bfr, acc, 0, 0, 0);
      }
      int colg = ch * 32 + w * 16 + lr;
#pragma unroll
      for (int jj = 0; jj < 4; ++jj) {
        int a_ = lg * 4 + jj;
        sS[a_ * 260 + colg] = (acc[jj] + sAB[a_]) * SCALE;
      }
    } else {
      int rt = w - 2;
      fx4 acc = {0.f, 0.f, 0.f, 0.f};
#pragma unroll
      for (int kt = 0; kt < 8; ++kt) {
        bfrag a = *(const bfrag*)&sHrm[(rt * 16 + lr) * 264 + kt * 32 + lk];
        bfrag bfr = *(const bfrag*)&sU[lr * 264 + kt * 32 + lk];
        acc = __builtin_amdgcn_mfma_f32_16x16x32_bf16(a, bfr, acc, 0, 0, 0);
      }
      float beta = sAB[16 + lr];
#pragma unroll
      for (int jj = 0; jj < 4; ++jj) {
        float s2 = (acc[jj] + beta) * SCALE;
        float m = s2;
        m = fmaxf(m, __shfl_xor(m, 1)); m = fmaxf(m, __shfl_xor(m, 2));
        m = fmaxf(m, __shfl_xor(m, 4)); m = fmaxf(m, __shfl_xor(m, 8));
        float e = __expf(s2 - m);
        float ssum = e;
        ssum += __shfl_xor(ssum, 1); ssum += __shfl_xor(ssum, 2);
        ssum += __shfl_xor(ssum, 4); ssum += __shfl_xor(ssum, 8);
        int crow = ch * 32 + rt * 16 + lg * 4 + jj;
        sP2[crow * 16 + lr] = f2b(e / ssum);
      }
    }
  }
  __syncthreads();

  // ---- ph3: softmax over c for the ads scores -> P (bf16) ----
  {
#pragma unroll
    for (int i = 0; i < 4; ++i) {
      int a_ = w * 4 + i;
      float4 v = *(const float4*)&sS[a_ * 260 + l * 4];
      float m = fmaxf(fmaxf(v.x, v.y), fmaxf(v.z, v.w));
      for (int mk = 1; mk < 64; mk <<= 1) m = fmaxf(m, __shfl_xor(m, mk));
      float e0 = __expf(v.x - m), e1 = __expf(v.y - m);
      float e2 = __expf(v.z - m), e3 = __expf(v.w - m);
      float s = e0 + e1 + e2 + e3;
      for (int mk = 1; mk < 64; mk <<= 1) s += __shfl_xor(s, mk);
      float rs = 1.f / s;
      ushort4 pk = make_ushort4(f2b(e0 * rs), f2b(e1 * rs), f2b(e2 * rs), f2b(e3 * rs));
      *(ushort4*)&sP[a_ * 264 + l * 4] = pk;
    }
  }
  __syncthreads();

  // ---- ph4: r = P @ h_cat (transposed+swizzled staging), then upd_ads ----
  fx4 racc[4] = {};
  for (int ch = 0; ch < 8; ++ch) {
    __syncthreads();
#pragma unroll
    for (int rep = 0; rep < 8; ++rep) {
      int i4 = rep * 256 + t;
      int c = i4 >> 6;
      int e0 = (i4 & 63) * 4;
      float4 v = *(const float4*)&h_cat[((size_t)b * NC_ + ch * 32 + c) * DD + e0];
      float vv[4] = {v.x, v.y, v.z, v.w};
#pragma unroll
      for (int m = 0; m < 4; ++m) {
        int e = e0 + m;
        int cs = (c & 7) | ((((c >> 3) ^ (e >> 2)) & 3) << 3);
        sHT[e * 40 + cs] = f2b(vv[m]);
      }
    }
    __syncthreads();
    bfrag a = *(const bfrag*)&sP[lr * 264 + ch * 32 + lk];
#pragma unroll
    for (int i = 0; i < 4; ++i) {
      int e = (w * 4 + i) * 16 + lr;
      int csb = (lg ^ ((e >> 2) & 3)) << 3;
      bfrag bfr = *(const bfrag*)&sHT[e * 40 + csb];
      racc[i] = __builtin_amdgcn_mfma_f32_16x16x32_bf16(a, bfr, racc[i], 0, 0, 0);
    }
  }
  __syncthreads();
#pragma unroll
  for (int i = 0; i < 4; ++i)
#pragma unroll
    for (int jj = 0; jj < 4; ++jj)
      sR[(lg * 4 + jj) * 264 + (w * 4 + i) * 16 + lr] = f2b(racc[i][jj]);
  __syncthreads();
  {
    const unsigned short* wv = wbf + 3 * 65536;
    float val[4][4];
    float ssq[4] = {0.f, 0.f, 0.f, 0.f};
#pragma unroll
    for (int i = 0; i < 4; ++i) {
      int gt = w * 4 + i;
      fx4 acc = {0.f, 0.f, 0.f, 0.f};
#pragma unroll
      for (int kt = 0; kt < 8; ++kt) {
        bfrag a = *(const bfrag*)&sR[lr * 264 + kt * 32 + lk];
        bfrag bfr = *(const bfrag*)&wv[(size_t)(gt * 16 + lr) * DD + kt * 32 + lk];
        acc = __builtin_amdgcn_mfma_f32_16x16x32_bf16(a, bfr, acc, 0, 0, 0);
      }
      int col = gt * 16 + lr;
      float bias = bv_cat[col];
#pragma unroll
      for (int jj = 0; jj < 4; ++jj) {
        int row = lg * 4 + jj;
        float hv = h_ads[((size_t)b * NA_ + row) * DD + col];
        float v = acc[jj] + bias + hv;
        val[i][jj] = v;
        ssq[jj] += v * v;
      }
    }
#pragma unroll
    for (int jj = 0; jj < 4; ++jj) {
      float s = ssq[jj];
      s += __shfl_xor(s, 1); s += __shfl_xor(s, 2);
      s += __shfl_xor(s, 4); s += __shfl_xor(s, 8);
      if (lr == 0) sRed[lg * 4 + jj][w] = s;
    }
    __syncthreads();
#pragma unroll
    for (int jj = 0; jj < 4; ++jj) {
      int row = lg * 4 + jj;
      float s = sRed[row][0] + sRed[row][1] + sRed[row][2] + sRed[row][3];
      float rn = 1.f / fmaxf(sqrtf(s), 1e-12f);
#pragma unroll
      for (int i = 0; i < 4; ++i) {
        int col = (w * 4 + i) * 16 + lr;
        out_ads[((size_t)b * NA_ + row) * DD + col] = val[i][jj] * rn;
      }
    }
  }

  // ---- ph5: cat outputs: out = normalize(h_cat + P2 @ v_ads) ----
  __syncthreads();
  {
    const unsigned short* vg = v_ads + (size_t)b * NA_ * DD;
#pragma unroll
    for (int rep = 0; rep < 4; ++rep) {
      int i4 = rep * 256 + t;
      int r = i4 >> 6, c = (i4 & 63) * 4;
      *(uint2*)&sV[r * 264 + c] = *(const uint2*)&vg[r * DD + c];
    }
  }
  __syncthreads();
  {
    float4 vv[16];
#pragma unroll
    for (int a_ = 0; a_ < 16; ++a_) {
      const unsigned short* p = &sV[a_ * 264 + l * 4];
      vv[a_] = make_float4(b2f(p[0]), b2f(p[1]), b2f(p[2]), b2f(p[3]));
    }
    for (int rr = 0; rr < 64; ++rr) {
      int crow = w * 64 + rr;
      const unsigned short* pp = &sP2[crow * 16];
      float4 h4 = *(const float4*)&h_cat[((size_t)b * NC_ + crow) * DD + l * 4];
      float ax = h4.x, ay = h4.y, az = h4.z, aw = h4.w;
#pragma unroll
      for (int a_ = 0; a_ < 16; ++a_) {
        float p = b2f(pp[a_]);
        ax += p * vv[a_].x; ay += p * vv[a_].y;
        az += p * vv[a_].z; aw += p * vv[a_].w;
      }
      float ss = ax * ax + ay * ay + az * az + aw * aw;
      for (int mk = 1; mk < 64; mk <<= 1) ss += __shfl_xor(ss, mk);
      float rn = 1.f / fmaxf(sqrtf(ss), 1e-12f);
      float4 o = make_float4(ax * rn, ay * rn, az * rn, aw * rn);
      *(float4*)&out_cat[((size_t)b * NC_ + crow) * DD + l * 4] = o;
    }
  }
}

extern "C" void kernel_launch(void* const* d_in, const int* in_sizes, int n_in,
                              void* d_out, int out_size, void* d_ws, size_t ws_size,
                              hipStream_t stream) {
  const float* h_ads = (const float*)d_in[0];
  const float* h_cat = (const float*)d_in[1];
  const float* Wq_ads = (const float*)d_in[2];
  const float* bq_ads = (const float*)d_in[3];
  const float* Wk_ads = (const float*)d_in[4];
  const float* bk_ads = (const float*)d_in[5];
  const float* Wv_ads = (const float*)d_in[6];
  const float* bv_ads = (const float*)d_in[7];
  const float* Wq_cat = (const float*)d_in[8];
  const float* bq_cat = (const float*)d_in[9];
  const float* Wk_cat = (const float*)d_in[10];
  const float* bk_cat = (const float*)d_in[11];
  const float* Wv_cat = (const float*)d_in[12];
  const float* bv_cat = (const float*)d_in[13];
  // batch_ads / batch_cat / n_graphs unused: segments are uniform (per reference note).

  unsigned short* wbf = (unsigned short*)d_ws;        // 6*65536 bf16 = 768 KB
  unsigned short* q_ads = wbf + 6 * 65536;            // 8192*256 bf16 each
  unsigned short* k_ads = q_ads + 8192 * 256;
  unsigned short* v_ads = k_ads + 8192 * 256;         // total ws use ~12.75 MB
  float* out_ads = (float*)d_out;
  float* out_cat = out_ads + 8192 * 256;

  prepW<<<1536, 256, 0, stream>>>(Wq_ads, Wk_ads, Wv_ads, Wv_cat, Wk_cat, Wq_cat, wbf);
  kA<<<128, 256, 0, stream>>>(h_ads, wbf, bq_ads, bk_ads, bv_ads, q_ads, k_ads, v_ads);
  kB<<<512, 256, 0, stream>>>(h_ads, h_cat, wbf, bq_cat, bk_cat, bv_cat,
                              q_ads, k_ads, v_ads, out_ads, out_cat);
}